// Round 1
// baseline (3624.311 us; speedup 1.0000x reference)
//
#include <hip/hip_runtime.h>
#include <cstdint>

#define N_NODES 100000
#define N_EDGES 3200000
#define F_IN 128
#define DIM 10
#define B_GRAPHS 1000

// p = x @ W[:128,:], q = x @ W[128:,:]  (one thread per node; W reads are
// wave-uniform -> compiler emits s_loads; x rows read as float4)
__global__ __launch_bounds__(256) void k_gemm1(
    const float* __restrict__ x, const float* __restrict__ W,
    float* __restrict__ p, float* __restrict__ q)
{
  int i = blockIdx.x * 256 + threadIdx.x;
  if (i >= N_NODES) return;
  const float4* __restrict__ xr = (const float4*)(x + (size_t)i * F_IN);
  float ap[DIM], aq[DIM];
  #pragma unroll
  for (int j = 0; j < DIM; ++j) { ap[j] = 0.f; aq[j] = 0.f; }
  #pragma unroll 4
  for (int k4 = 0; k4 < F_IN / 4; ++k4) {
    float4 v = xr[k4];
    const float* __restrict__ w0 = W + (k4 * 4) * DIM;
    const float* __restrict__ w1 = W + (F_IN + k4 * 4) * DIM;
    #pragma unroll
    for (int j = 0; j < DIM; ++j) {
      ap[j] += v.x * w0[j] + v.y * w0[DIM + j] + v.z * w0[2 * DIM + j] + v.w * w0[3 * DIM + j];
      aq[j] += v.x * w1[j] + v.y * w1[DIM + j] + v.z * w1[2 * DIM + j] + v.w * w1[3 * DIM + j];
    }
  }
  #pragma unroll
  for (int j = 0; j < DIM; ++j) {
    p[(size_t)i * DIM + j] = ap[j];
    q[(size_t)i * DIM + j] = aq[j];
  }
}

__global__ __launch_bounds__(256) void k_deg(const int* __restrict__ dst,
                                             float* __restrict__ deg)
{
  int e = blockIdx.x * 256 + threadIdx.x;
  if (e < N_EDGES) atomicAdd(&deg[dst[e]], 1.0f);
}

// scatter-add q[src] into agg[dst]
__global__ __launch_bounds__(256) void k_agg(
    const int* __restrict__ src, const int* __restrict__ dst,
    const float* __restrict__ q, float* __restrict__ agg)
{
  int e = blockIdx.x * 256 + threadIdx.x;
  if (e >= N_EDGES) return;
  int s = src[e], d = dst[e];
  const float* __restrict__ qr = q + (size_t)s * DIM;
  float* ar = agg + (size_t)d * DIM;
  #pragma unroll
  for (int j = 0; j < DIM; ++j) atomicAdd(&ar[j], qr[j]);
}

// h = relu(p1 + agg1/deg); p2 = h @ W2[:10,:], q2 = h @ W2[10:,:]
__global__ __launch_bounds__(256) void k_l1fin(
    const float* __restrict__ p1, const float* __restrict__ agg1,
    const float* __restrict__ deg, const float* __restrict__ W2,
    float* __restrict__ p2, float* __restrict__ q2)
{
  __shared__ float w[2 * DIM * DIM];
  for (int t = threadIdx.x; t < 2 * DIM * DIM; t += 256) w[t] = W2[t];
  __syncthreads();
  int i = blockIdx.x * 256 + threadIdx.x;
  if (i >= N_NODES) return;
  float inv = 1.0f / fmaxf(deg[i], 1.0f);
  float h[DIM];
  #pragma unroll
  for (int j = 0; j < DIM; ++j) {
    float v = p1[(size_t)i * DIM + j] + agg1[(size_t)i * DIM + j] * inv;
    h[j] = fmaxf(v, 0.0f);
  }
  #pragma unroll
  for (int j = 0; j < DIM; ++j) {
    float a = 0.f, b = 0.f;
    #pragma unroll
    for (int k = 0; k < DIM; ++k) {
      a += h[k] * w[k * DIM + j];
      b += h[k] * w[(DIM + k) * DIM + j];
    }
    p2[(size_t)i * DIM + j] = a;
    q2[(size_t)i * DIM + j] = b;
  }
}

// h2 = p2 + agg2/deg; pool: gsum[batch[i]] += h2, bcount[batch[i]] += 1
__global__ __launch_bounds__(256) void k_l2fin(
    const float* __restrict__ p2, const float* __restrict__ agg2,
    const float* __restrict__ deg, const int* __restrict__ batch,
    float* __restrict__ gsum, float* __restrict__ bcount)
{
  int i = blockIdx.x * 256 + threadIdx.x;
  if (i >= N_NODES) return;
  float inv = 1.0f / fmaxf(deg[i], 1.0f);
  int b = batch[i];
  float* g = gsum + (size_t)b * DIM;
  #pragma unroll
  for (int j = 0; j < DIM; ++j)
    atomicAdd(&g[j], p2[(size_t)i * DIM + j] + agg2[(size_t)i * DIM + j] * inv);
  atomicAdd(&bcount[b], 1.0f);
}

__global__ __launch_bounds__(256) void k_out(
    const float* __restrict__ gsum, const float* __restrict__ bcount,
    const float* __restrict__ Wfc, float* __restrict__ out)
{
  int b = blockIdx.x * 256 + threadIdx.x;
  if (b >= B_GRAPHS) return;
  float inv = 1.0f / fmaxf(bcount[b], 1.0f);
  float acc = 0.f;
  #pragma unroll
  for (int j = 0; j < DIM; ++j) acc += gsum[(size_t)b * DIM + j] * inv * Wfc[j];
  out[b] = 1.0f / (1.0f + expf(-acc));
}

extern "C" void kernel_launch(void* const* d_in, const int* in_sizes, int n_in,
                              void* d_out, int out_size, void* d_ws, size_t ws_size,
                              hipStream_t stream)
{
  const float* x    = (const float*)d_in[0];
  const int*   ei   = (const int*)d_in[1];
  const int*   batch= (const int*)d_in[2];
  const float* W1   = (const float*)d_in[3];
  const float* W2   = (const float*)d_in[4];
  const float* Wfc  = (const float*)d_in[5];
  float* out = (float*)d_out;

  const int* src = ei;            // edge_index[0]
  const int* dst = ei + N_EDGES;  // edge_index[1]

  float* ws    = (float*)d_ws;
  float* agg1  = ws;                        // N*DIM
  float* agg2  = agg1 + (size_t)N_NODES * DIM;
  float* deg   = agg2 + (size_t)N_NODES * DIM;   // N
  float* bcount= deg + N_NODES;                  // B
  float* gsum  = bcount + B_GRAPHS;              // B*DIM
  float* p1    = gsum + (size_t)B_GRAPHS * DIM;  // N*DIM
  float* q1    = p1 + (size_t)N_NODES * DIM;
  float* p2    = q1 + (size_t)N_NODES * DIM;
  float* q2    = p2 + (size_t)N_NODES * DIM;

  size_t zero_floats = (size_t)2 * N_NODES * DIM + N_NODES + B_GRAPHS
                     + (size_t)B_GRAPHS * DIM;
  hipMemsetAsync(d_ws, 0, zero_floats * sizeof(float), stream);

  int nb_n = (N_NODES + 255) / 256;
  int nb_e = (N_EDGES + 255) / 256;
  k_gemm1<<<nb_n, 256, 0, stream>>>(x, W1, p1, q1);
  k_deg  <<<nb_e, 256, 0, stream>>>(dst, deg);
  k_agg  <<<nb_e, 256, 0, stream>>>(src, dst, q1, agg1);
  k_l1fin<<<nb_n, 256, 0, stream>>>(p1, agg1, deg, W2, p2, q2);
  k_agg  <<<nb_e, 256, 0, stream>>>(src, dst, q2, agg2);
  k_l2fin<<<nb_n, 256, 0, stream>>>(p2, agg2, deg, batch, gsum, bcount);
  k_out  <<<(B_GRAPHS + 255) / 256, 256, 0, stream>>>(gsum, bcount, Wfc, out);
}

// Round 2
// 687.832 us; speedup vs baseline: 5.2692x; 5.2692x over previous
//
#include <hip/hip_runtime.h>
#include <cstdint>

#define N_NODES 100000
#define N_EDGES 3200000
#define F_IN 128
#define DIM 10
#define QPAD 12          // q rows padded to 12 floats -> 48B, float4-aligned
#define B_GRAPHS 1000
#define NBLK_N 391       // ceil(100000/256)

// p = x @ W[:128,:], q = x @ W[128:,:]  (q written with padded stride)
__global__ __launch_bounds__(256) void k_gemm1(
    const float* __restrict__ x, const float* __restrict__ W,
    float* __restrict__ p, float* __restrict__ qp)
{
  int i = blockIdx.x * 256 + threadIdx.x;
  if (i >= N_NODES) return;
  const float4* __restrict__ xr = (const float4*)(x + (size_t)i * F_IN);
  float ap[DIM], aq[DIM];
  #pragma unroll
  for (int j = 0; j < DIM; ++j) { ap[j] = 0.f; aq[j] = 0.f; }
  #pragma unroll 4
  for (int k4 = 0; k4 < F_IN / 4; ++k4) {
    float4 v = xr[k4];
    const float* __restrict__ w0 = W + (k4 * 4) * DIM;
    const float* __restrict__ w1 = W + (F_IN + k4 * 4) * DIM;
    #pragma unroll
    for (int j = 0; j < DIM; ++j) {
      ap[j] += v.x * w0[j] + v.y * w0[DIM + j] + v.z * w0[2 * DIM + j] + v.w * w0[3 * DIM + j];
      aq[j] += v.x * w1[j] + v.y * w1[DIM + j] + v.z * w1[2 * DIM + j] + v.w * w1[3 * DIM + j];
    }
  }
  #pragma unroll
  for (int j = 0; j < DIM; ++j) p[(size_t)i * DIM + j] = ap[j];
  #pragma unroll
  for (int j = 0; j < DIM; ++j) qp[(size_t)i * QPAD + j] = aq[j];
  qp[(size_t)i * QPAD + 10] = 0.f;
  qp[(size_t)i * QPAD + 11] = 0.f;
}

__global__ __launch_bounds__(256) void k_hist(const int* __restrict__ dst,
                                              int* __restrict__ deg)
{
  int e = blockIdx.x * 256 + threadIdx.x;
  if (e < N_EDGES) atomicAdd(&deg[dst[e]], 1);
}

// block-local inclusive scan of deg -> rowptr[i+1]; block totals -> bsum
__global__ __launch_bounds__(256) void k_scanA(const int* __restrict__ deg,
                                               int* __restrict__ rowptr,
                                               int* __restrict__ bsum)
{
  __shared__ int s[256];
  int t = threadIdx.x;
  int i = blockIdx.x * 256 + t;
  s[t] = (i < N_NODES) ? deg[i] : 0;
  __syncthreads();
  #pragma unroll
  for (int off = 1; off < 256; off <<= 1) {
    int add = (t >= off) ? s[t - off] : 0;
    __syncthreads();
    s[t] += add;
    __syncthreads();
  }
  if (i < N_NODES) rowptr[i + 1] = s[t];
  if (t == 255) bsum[blockIdx.x] = s[255];
}

// exclusive scan of the 391 block sums -> boff
__global__ __launch_bounds__(512) void k_scanB(const int* __restrict__ bsum,
                                               int* __restrict__ boff)
{
  __shared__ int s[512];
  int t = threadIdx.x;
  s[t] = (t < NBLK_N) ? bsum[t] : 0;
  __syncthreads();
  #pragma unroll
  for (int off = 1; off < 512; off <<= 1) {
    int add = (t >= off) ? s[t - off] : 0;
    __syncthreads();
    s[t] += add;
    __syncthreads();
  }
  if (t < NBLK_N) boff[t] = (t == 0) ? 0 : s[t - 1];
}

__global__ __launch_bounds__(256) void k_scanC(int* __restrict__ rowptr,
                                               const int* __restrict__ boff)
{
  int i = blockIdx.x * 256 + threadIdx.x;
  if (i < N_NODES) rowptr[i + 1] += boff[blockIdx.x];
  if (i == 0) rowptr[0] = 0;
}

__global__ __launch_bounds__(256) void k_fill(
    const int* __restrict__ src, const int* __restrict__ dst,
    const int* __restrict__ rowptr, int* __restrict__ cursor,
    int* __restrict__ csr_src)
{
  int e = blockIdx.x * 256 + threadIdx.x;
  if (e >= N_EDGES) return;
  int d = dst[e];
  int pos = rowptr[d] + atomicAdd(&cursor[d], 1);
  csr_src[pos] = src[e];
}

// gather-aggregate q1 per node, fuse relu(p1 + mean) and @W2 -> p2, q2p
__global__ __launch_bounds__(256) void k_l1(
    const int* __restrict__ rowptr, const int* __restrict__ csr_src,
    const float* __restrict__ p1, const float* __restrict__ q1p,
    const float* __restrict__ W2,
    float* __restrict__ p2, float* __restrict__ q2p)
{
  __shared__ float w[2 * DIM * DIM];
  for (int t = threadIdx.x; t < 2 * DIM * DIM; t += 256) w[t] = W2[t];
  __syncthreads();
  int i = blockIdx.x * 256 + threadIdx.x;
  if (i >= N_NODES) return;
  int beg = rowptr[i], end = rowptr[i + 1];
  float4 a0 = {0, 0, 0, 0}, a1 = {0, 0, 0, 0};
  float s8 = 0.f, s9 = 0.f;
  for (int e = beg; e < end; ++e) {
    int s = csr_src[e];
    const float4* __restrict__ r = (const float4*)(q1p + (size_t)s * QPAD);
    float4 r0 = r[0], r1 = r[1], r2 = r[2];
    a0.x += r0.x; a0.y += r0.y; a0.z += r0.z; a0.w += r0.w;
    a1.x += r1.x; a1.y += r1.y; a1.z += r1.z; a1.w += r1.w;
    s8 += r2.x; s9 += r2.y;
  }
  float inv = 1.0f / fmaxf((float)(end - beg), 1.0f);
  float h[DIM];
  float sum[DIM] = {a0.x, a0.y, a0.z, a0.w, a1.x, a1.y, a1.z, a1.w, s8, s9};
  #pragma unroll
  for (int j = 0; j < DIM; ++j)
    h[j] = fmaxf(p1[(size_t)i * DIM + j] + sum[j] * inv, 0.0f);
  #pragma unroll
  for (int j = 0; j < DIM; ++j) {
    float a = 0.f, b = 0.f;
    #pragma unroll
    for (int k = 0; k < DIM; ++k) {
      a += h[k] * w[k * DIM + j];
      b += h[k] * w[(DIM + k) * DIM + j];
    }
    p2[(size_t)i * DIM + j] = a;
    q2p[(size_t)i * QPAD + j] = b;
  }
  q2p[(size_t)i * QPAD + 10] = 0.f;
  q2p[(size_t)i * QPAD + 11] = 0.f;
}

// gather-aggregate q2 per node, fuse mean + global pool atomics
__global__ __launch_bounds__(256) void k_l2(
    const int* __restrict__ rowptr, const int* __restrict__ csr_src,
    const float* __restrict__ p2, const float* __restrict__ q2p,
    const int* __restrict__ batch,
    float* __restrict__ gsum, float* __restrict__ bcount)
{
  int i = blockIdx.x * 256 + threadIdx.x;
  if (i >= N_NODES) return;
  int beg = rowptr[i], end = rowptr[i + 1];
  float4 a0 = {0, 0, 0, 0}, a1 = {0, 0, 0, 0};
  float s8 = 0.f, s9 = 0.f;
  for (int e = beg; e < end; ++e) {
    int s = csr_src[e];
    const float4* __restrict__ r = (const float4*)(q2p + (size_t)s * QPAD);
    float4 r0 = r[0], r1 = r[1], r2 = r[2];
    a0.x += r0.x; a0.y += r0.y; a0.z += r0.z; a0.w += r0.w;
    a1.x += r1.x; a1.y += r1.y; a1.z += r1.z; a1.w += r1.w;
    s8 += r2.x; s9 += r2.y;
  }
  float inv = 1.0f / fmaxf((float)(end - beg), 1.0f);
  float sum[DIM] = {a0.x, a0.y, a0.z, a0.w, a1.x, a1.y, a1.z, a1.w, s8, s9};
  int b = batch[i];
  float* g = gsum + (size_t)b * DIM;
  #pragma unroll
  for (int j = 0; j < DIM; ++j)
    atomicAdd(&g[j], p2[(size_t)i * DIM + j] + sum[j] * inv);
  atomicAdd(&bcount[b], 1.0f);
}

__global__ __launch_bounds__(256) void k_out(
    const float* __restrict__ gsum, const float* __restrict__ bcount,
    const float* __restrict__ Wfc, float* __restrict__ out)
{
  int b = blockIdx.x * 256 + threadIdx.x;
  if (b >= B_GRAPHS) return;
  float inv = 1.0f / fmaxf(bcount[b], 1.0f);
  float acc = 0.f;
  #pragma unroll
  for (int j = 0; j < DIM; ++j) acc += gsum[(size_t)b * DIM + j] * inv * Wfc[j];
  out[b] = 1.0f / (1.0f + expf(-acc));
}

extern "C" void kernel_launch(void* const* d_in, const int* in_sizes, int n_in,
                              void* d_out, int out_size, void* d_ws, size_t ws_size,
                              hipStream_t stream)
{
  const float* x     = (const float*)d_in[0];
  const int*   ei    = (const int*)d_in[1];
  const int*   batch = (const int*)d_in[2];
  const float* W1    = (const float*)d_in[3];
  const float* W2    = (const float*)d_in[4];
  const float* Wfc   = (const float*)d_in[5];
  float* out = (float*)d_out;

  const int* src = ei;            // edge_index[0]
  const int* dst = ei + N_EDGES;  // edge_index[1]

  // ---- workspace layout (all 4-byte elems; zero region first, then
  //      float4-aligned q arrays: every offset below is a multiple of 4) ----
  int* ip = (int*)d_ws;
  int*   deg    = ip;                         // N      (zeroed)
  int*   cursor = ip + N_NODES;               // N      (zeroed)
  float* gsum   = (float*)(ip + 2 * N_NODES); // B*DIM  (zeroed)
  float* bcount = gsum + B_GRAPHS * DIM;      // B      (zeroed)
  const size_t zero_elems = 2 * N_NODES + B_GRAPHS * DIM + B_GRAPHS; // 211000

  float* q1p   = bcount + B_GRAPHS;                 // N*12 (offset 211000, %4==0)
  float* q2p   = q1p + (size_t)N_NODES * QPAD;      // N*12
  float* p1    = q2p + (size_t)N_NODES * QPAD;      // N*10
  float* p2    = p1 + (size_t)N_NODES * DIM;        // N*10
  int*   rowptr= (int*)(p2 + (size_t)N_NODES * DIM);// N+1
  int*   bsum  = rowptr + N_NODES + 1;              // NBLK_N
  int*   boff  = bsum + NBLK_N;                     // NBLK_N
  int*   csr   = boff + NBLK_N;                     // E

  hipMemsetAsync(d_ws, 0, zero_elems * sizeof(float), stream);

  int nb_n = NBLK_N;
  int nb_e = (N_EDGES + 255) / 256;
  k_gemm1<<<nb_n, 256, 0, stream>>>(x, W1, p1, q1p);
  k_hist <<<nb_e, 256, 0, stream>>>(dst, deg);
  k_scanA<<<nb_n, 256, 0, stream>>>(deg, rowptr, bsum);
  k_scanB<<<1, 512, 0, stream>>>(bsum, boff);
  k_scanC<<<nb_n, 256, 0, stream>>>(rowptr, boff);
  k_fill <<<nb_e, 256, 0, stream>>>(src, dst, rowptr, cursor, csr);
  k_l1   <<<nb_n, 256, 0, stream>>>(rowptr, csr, p1, q1p, W2, p2, q2p);
  k_l2   <<<nb_n, 256, 0, stream>>>(rowptr, csr, p2, q2p, batch, gsum, bcount);
  k_out  <<<(B_GRAPHS + 255) / 256, 256, 0, stream>>>(gsum, bcount, Wfc, out);
}

// Round 3
// 607.226 us; speedup vs baseline: 5.9686x; 1.1327x over previous
//
#include <hip/hip_runtime.h>
#include <cstdint>

#define N_NODES 100000
#define N_EDGES 3200000
#define F_IN 128
#define DIM 10
#define QPAD 12          // padded row: 12 floats = 48B = 3 x float4
#define B_GRAPHS 1000
#define NBLK_N 391       // ceil(100000/256)
#define G 8              // lanes per node in gather kernels

// p1p = x @ W[:128,:], q1p = x @ W[128:,:]  (both stride-12 padded)
__global__ __launch_bounds__(256) void k_gemm1(
    const float* __restrict__ x, const float* __restrict__ W,
    float* __restrict__ p1p, float* __restrict__ q1p)
{
  int i = blockIdx.x * 256 + threadIdx.x;
  if (i >= N_NODES) return;
  const float4* __restrict__ xr = (const float4*)(x + (size_t)i * F_IN);
  float ap[DIM], aq[DIM];
  #pragma unroll
  for (int j = 0; j < DIM; ++j) { ap[j] = 0.f; aq[j] = 0.f; }
  #pragma unroll 4
  for (int k4 = 0; k4 < F_IN / 4; ++k4) {
    float4 v = xr[k4];
    const float* __restrict__ w0 = W + (k4 * 4) * DIM;
    const float* __restrict__ w1 = W + (F_IN + k4 * 4) * DIM;
    #pragma unroll
    for (int j = 0; j < DIM; ++j) {
      ap[j] += v.x * w0[j] + v.y * w0[DIM + j] + v.z * w0[2 * DIM + j] + v.w * w0[3 * DIM + j];
      aq[j] += v.x * w1[j] + v.y * w1[DIM + j] + v.z * w1[2 * DIM + j] + v.w * w1[3 * DIM + j];
    }
  }
  float* pr = p1p + (size_t)i * QPAD;
  float* qr = q1p + (size_t)i * QPAD;
  #pragma unroll
  for (int j = 0; j < DIM; ++j) { pr[j] = ap[j]; qr[j] = aq[j]; }
  pr[10] = 0.f; pr[11] = 0.f; qr[10] = 0.f; qr[11] = 0.f;
}

__global__ __launch_bounds__(256) void k_hist(const int* __restrict__ dst,
                                              int* __restrict__ deg)
{
  int e = blockIdx.x * 256 + threadIdx.x;
  if (e < N_EDGES) atomicAdd(&deg[dst[e]], 1);
}

__global__ __launch_bounds__(256) void k_scanA(const int* __restrict__ deg,
                                               int* __restrict__ rowptr,
                                               int* __restrict__ bsum)
{
  __shared__ int s[256];
  int t = threadIdx.x;
  int i = blockIdx.x * 256 + t;
  s[t] = (i < N_NODES) ? deg[i] : 0;
  __syncthreads();
  #pragma unroll
  for (int off = 1; off < 256; off <<= 1) {
    int add = (t >= off) ? s[t - off] : 0;
    __syncthreads();
    s[t] += add;
    __syncthreads();
  }
  if (i < N_NODES) rowptr[i + 1] = s[t];
  if (t == 255) bsum[blockIdx.x] = s[255];
}

__global__ __launch_bounds__(512) void k_scanB(const int* __restrict__ bsum,
                                               int* __restrict__ boff)
{
  __shared__ int s[512];
  int t = threadIdx.x;
  s[t] = (t < NBLK_N) ? bsum[t] : 0;
  __syncthreads();
  #pragma unroll
  for (int off = 1; off < 512; off <<= 1) {
    int add = (t >= off) ? s[t - off] : 0;
    __syncthreads();
    s[t] += add;
    __syncthreads();
  }
  if (t < NBLK_N) boff[t] = (t == 0) ? 0 : s[t - 1];
}

// finalize rowptr and seed cur[i] = rowptr[i] (fill cursor)
__global__ __launch_bounds__(256) void k_scanC(int* __restrict__ rowptr,
                                               const int* __restrict__ boff,
                                               const int* __restrict__ deg,
                                               int* __restrict__ cur)
{
  int i = blockIdx.x * 256 + threadIdx.x;
  if (i >= N_NODES) return;
  int v = rowptr[i + 1] + boff[blockIdx.x];
  rowptr[i + 1] = v;
  cur[i] = v - deg[i];
  if (i == 0) rowptr[0] = 0;
}

__global__ __launch_bounds__(256) void k_fill(
    const int* __restrict__ src, const int* __restrict__ dst,
    int* __restrict__ cur, int* __restrict__ csr_src)
{
  int e = blockIdx.x * 256 + threadIdx.x;
  if (e >= N_EDGES) return;
  int pos = atomicAdd(&cur[dst[e]], 1);
  csr_src[pos] = src[e];
}

// layer-1 gather: G lanes per node; fuse relu(p1+mean) and @W2 -> p2p, q2p
__global__ __launch_bounds__(256) void k_l1(
    const int* __restrict__ rowptr, const int* __restrict__ csr_src,
    const float* __restrict__ p1p, const float* __restrict__ q1p,
    const float* __restrict__ W2,
    float* __restrict__ p2p, float* __restrict__ q2p)
{
  __shared__ float w[2 * DIM * DIM];
  for (int t = threadIdx.x; t < 2 * DIM * DIM; t += 256) w[t] = W2[t];
  __syncthreads();
  int lane = threadIdx.x & (G - 1);
  int i = blockIdx.x * (256 / G) + (threadIdx.x >> 3);
  if (i >= N_NODES) return;
  int beg = rowptr[i], end = rowptr[i + 1];
  float sum[DIM];
  #pragma unroll
  for (int j = 0; j < DIM; ++j) sum[j] = 0.f;
  for (int e = beg + lane; e < end; e += G) {
    int s = csr_src[e];
    const float4* __restrict__ r = (const float4*)(q1p + (size_t)s * QPAD);
    float4 r0 = r[0], r1 = r[1];
    float2 r2 = *(const float2*)(q1p + (size_t)s * QPAD + 8);
    sum[0] += r0.x; sum[1] += r0.y; sum[2] += r0.z; sum[3] += r0.w;
    sum[4] += r1.x; sum[5] += r1.y; sum[6] += r1.z; sum[7] += r1.w;
    sum[8] += r2.x; sum[9] += r2.y;
  }
  #pragma unroll
  for (int m = 1; m < G; m <<= 1) {
    #pragma unroll
    for (int j = 0; j < DIM; ++j) sum[j] += __shfl_xor(sum[j], m, G);
  }
  float inv = 1.0f / fmaxf((float)(end - beg), 1.0f);
  const float* __restrict__ pr = p1p + (size_t)i * QPAD;
  float h[DIM];
  #pragma unroll
  for (int j = 0; j < DIM; ++j) h[j] = fmaxf(pr[j] + sum[j] * inv, 0.0f);
  float a[DIM], b[DIM];
  #pragma unroll
  for (int j = 0; j < DIM; ++j) {
    float aa = 0.f, bb = 0.f;
    #pragma unroll
    for (int k = 0; k < DIM; ++k) {
      aa += h[k] * w[k * DIM + j];
      bb += h[k] * w[(DIM + k) * DIM + j];
    }
    a[j] = aa; b[j] = bb;
  }
  if (lane == 0) {
    float* po = p2p + (size_t)i * QPAD;
    float* qo = q2p + (size_t)i * QPAD;
    #pragma unroll
    for (int j = 0; j < DIM; ++j) { po[j] = a[j]; qo[j] = b[j]; }
    po[10] = 0.f; po[11] = 0.f; qo[10] = 0.f; qo[11] = 0.f;
  }
}

// layer-2 gather: h2 = p2 + mean(q2[src]); store h2 rows (no atomics)
__global__ __launch_bounds__(256) void k_l2(
    const int* __restrict__ rowptr, const int* __restrict__ csr_src,
    const float* __restrict__ p2p, const float* __restrict__ q2p,
    float* __restrict__ h2)
{
  int lane = threadIdx.x & (G - 1);
  int i = blockIdx.x * (256 / G) + (threadIdx.x >> 3);
  if (i >= N_NODES) return;
  int beg = rowptr[i], end = rowptr[i + 1];
  float sum[DIM];
  #pragma unroll
  for (int j = 0; j < DIM; ++j) sum[j] = 0.f;
  for (int e = beg + lane; e < end; e += G) {
    int s = csr_src[e];
    const float4* __restrict__ r = (const float4*)(q2p + (size_t)s * QPAD);
    float4 r0 = r[0], r1 = r[1];
    float2 r2 = *(const float2*)(q2p + (size_t)s * QPAD + 8);
    sum[0] += r0.x; sum[1] += r0.y; sum[2] += r0.z; sum[3] += r0.w;
    sum[4] += r1.x; sum[5] += r1.y; sum[6] += r1.z; sum[7] += r1.w;
    sum[8] += r2.x; sum[9] += r2.y;
  }
  #pragma unroll
  for (int m = 1; m < G; m <<= 1) {
    #pragma unroll
    for (int j = 0; j < DIM; ++j) sum[j] += __shfl_xor(sum[j], m, G);
  }
  if (lane == 0) {
    float inv = 1.0f / fmaxf((float)(end - beg), 1.0f);
    const float* __restrict__ pr = p2p + (size_t)i * QPAD;
    float* ho = h2 + (size_t)i * QPAD;
    #pragma unroll
    for (int j = 0; j < DIM; ++j) ho[j] = pr[j] + sum[j] * inv;
    ho[10] = 0.f; ho[11] = 0.f;
  }
}

// one wave per graph: binary-search node range in sorted batch, mean-pool,
// dot with Wfc, sigmoid -> out[b]. Zero atomics.
__global__ __launch_bounds__(64) void k_pool(
    const float* __restrict__ h2, const int* __restrict__ batch,
    const float* __restrict__ Wfc, float* __restrict__ out)
{
  int b = blockIdx.x;
  int lo = 0, hi = N_NODES;
  while (lo < hi) { int m = (lo + hi) >> 1; if (batch[m] < b) lo = m + 1; else hi = m; }
  int start = lo;
  hi = N_NODES;
  while (lo < hi) { int m = (lo + hi) >> 1; if (batch[m] < b + 1) lo = m + 1; else hi = m; }
  int end = lo;
  float sum[DIM];
  #pragma unroll
  for (int j = 0; j < DIM; ++j) sum[j] = 0.f;
  for (int r = start + threadIdx.x; r < end; r += 64) {
    const float4* __restrict__ p = (const float4*)(h2 + (size_t)r * QPAD);
    float4 r0 = p[0], r1 = p[1];
    float2 r2 = *(const float2*)(h2 + (size_t)r * QPAD + 8);
    sum[0] += r0.x; sum[1] += r0.y; sum[2] += r0.z; sum[3] += r0.w;
    sum[4] += r1.x; sum[5] += r1.y; sum[6] += r1.z; sum[7] += r1.w;
    sum[8] += r2.x; sum[9] += r2.y;
  }
  #pragma unroll
  for (int m = 1; m < 64; m <<= 1) {
    #pragma unroll
    for (int j = 0; j < DIM; ++j) sum[j] += __shfl_xor(sum[j], m, 64);
  }
  if (threadIdx.x == 0) {
    float inv = 1.0f / fmaxf((float)(end - start), 1.0f);
    float acc = 0.f;
    #pragma unroll
    for (int j = 0; j < DIM; ++j) acc += sum[j] * inv * Wfc[j];
    out[b] = 1.0f / (1.0f + expf(-acc));
  }
}

extern "C" void kernel_launch(void* const* d_in, const int* in_sizes, int n_in,
                              void* d_out, int out_size, void* d_ws, size_t ws_size,
                              hipStream_t stream)
{
  const float* x     = (const float*)d_in[0];
  const int*   ei    = (const int*)d_in[1];
  const int*   batch = (const int*)d_in[2];
  const float* W1    = (const float*)d_in[3];
  const float* W2    = (const float*)d_in[4];
  const float* Wfc   = (const float*)d_in[5];
  float* out = (float*)d_out;

  const int* src = ei;            // edge_index[0]
  const int* dst = ei + N_EDGES;  // edge_index[1]

  // ---- workspace layout (element offsets; padded arrays 16B-aligned) ----
  int* ip = (int*)d_ws;
  int* deg    = ip;                        // N     (zeroed)
  int* cur    = deg + N_NODES;             // N     (written by scanC)
  int* rowptr = cur + N_NODES;             // N+1
  int* bsum   = rowptr + N_NODES + 4;      // 392 (rounded)
  int* boff   = bsum + 392;                // 392
  int* csr    = boff + 392;                // E
  float* q1p  = (float*)(csr + N_EDGES);   // N*12 (offset 3500788, %4==0)
  float* q2p  = q1p + (size_t)N_NODES * QPAD;
  float* p1p  = q2p + (size_t)N_NODES * QPAD;
  float* p2p  = p1p + (size_t)N_NODES * QPAD;
  float* h2   = q1p;                       // reuse: q1p dead after k_l1

  hipMemsetAsync(deg, 0, N_NODES * sizeof(int), stream);

  int nb_n = NBLK_N;
  int nb_e = (N_EDGES + 255) / 256;
  int nb_g = (N_NODES * G + 255) / 256;   // gather kernels: G lanes/node
  k_gemm1<<<nb_n, 256, 0, stream>>>(x, W1, p1p, q1p);
  k_hist <<<nb_e, 256, 0, stream>>>(dst, deg);
  k_scanA<<<nb_n, 256, 0, stream>>>(deg, rowptr, bsum);
  k_scanB<<<1, 512, 0, stream>>>(bsum, boff);
  k_scanC<<<nb_n, 256, 0, stream>>>(rowptr, boff, deg, cur);
  k_fill <<<nb_e, 256, 0, stream>>>(src, dst, cur, csr);
  k_l1   <<<nb_g, 256, 0, stream>>>(rowptr, csr, p1p, q1p, W2, p2p, q2p);
  k_l2   <<<nb_g, 256, 0, stream>>>(rowptr, csr, p2p, q2p, h2);
  k_pool <<<B_GRAPHS, 64, 0, stream>>>(h2, batch, Wfc, out);
}